// Round 15
// baseline (472.053 us; speedup 1.0000x reference)
//
#include <hip/hip_runtime.h>

// Problem constants (B=2, L=16, D=4, K=2, N_IN=8, N_OUT=8, NC=3)
#define NSITES (1 << 17)         // 131072 sites (2*16^4)
// W:     site-stride 72 floats (18 float4), base 288 B
// U_PT:  site-stride 180 floats
// omega: flat [i][j][mu][ik] (1280 floats)
// out:   site-stride 72 floats
//
// R15 = R12 body re-tiled for residency (the dur*VALUBusy ~= 48us law):
//   - 512-thread blocks, 64 sites each -> omega LDS amortized;
//     LDS = 1312 + 64*184 = 13088 floats = 52.4 KB -> 3 blocks/CU
//     = 24 waves/CU (vs 20 theoretical / 9 measured at R12's tiling).
//   - __launch_bounds__(512, 6): VGPR cap 85 >= natural 72 -> no spill
//     (R14's (256,8) forced cap 64 -> 32 VGPR + 167MB scratch disaster).
//   - Body identical to R12: 8 thr/site = (jh,mu), sandwich-first,
//     partner-M via shfl_xor(4), JIT W float4 stream, LDS U + omega.

#define OM_OFF 0                 // [mu][ik][j][i]: mu-stride 328
#define U_OFF  1312              // [site][184] (pad 180)
#define NSITE_BLK 64
#define LDS_FLOATS (U_OFF + NSITE_BLK * 184)   // 13088 floats = 52352 B

// sandwich channel T (9 row-major floats) + omega-mix into acc
#define DO_CH(T, w0,w1,w2,w3,w4,w5,w6,w7,w8) do {                           \
    float M[9];                                                             \
    _Pragma("unroll")                                                       \
    for (int a = 0; a < 3; ++a) {                                           \
        const float uw0 = fmaf(U[a*3+0], (w0),                              \
                          fmaf(U[a*3+1], (w3), U[a*3+2] * (w6)));           \
        const float uw1 = fmaf(U[a*3+0], (w1),                              \
                          fmaf(U[a*3+1], (w4), U[a*3+2] * (w7)));           \
        const float uw2 = fmaf(U[a*3+0], (w2),                              \
                          fmaf(U[a*3+1], (w5), U[a*3+2] * (w8)));           \
        _Pragma("unroll")                                                   \
        for (int b2 = 0; b2 < 3; ++b2)                                      \
            M[a*3+b2] = fmaf(uw0, U[b2*3+0],                                \
                        fmaf(uw1, U[b2*3+1], uw2 * U[b2*3+2]));             \
    }                                                                       \
    const float4 wo = *reinterpret_cast<const float4*>(                     \
                          omt + ik * 64 + jown8 + (T) * 8);                 \
    const float4 wp = *reinterpret_cast<const float4*>(                     \
                          omt + ik * 64 + jpar8 + (T) * 8);                 \
    const float wov[4] = {wo.x, wo.y, wo.z, wo.w};                          \
    const float wpv[4] = {wp.x, wp.y, wp.z, wp.w};                          \
    _Pragma("unroll")                                                       \
    for (int e = 0; e < 9; ++e) {                                           \
        const float mp = __shfl_xor(M[e], 4);                               \
        _Pragma("unroll")                                                   \
        for (int ii = 0; ii < 4; ++ii)                                      \
            acc[ii][e] = fmaf(wov[ii], M[e], fmaf(wpv[ii], mp, acc[ii][e]));\
    }                                                                       \
} while (0)

__global__ __launch_bounds__(512, 6) void lconv_kernel(
    const float* __restrict__ W, const float* __restrict__ U_PT,
    const float* __restrict__ omega, float* __restrict__ out)
{
    __shared__ float lds[LDS_FLOATS];
    const int tid = threadIdx.x;

    // XCD-aware bijective swizzle: 2048 blocks, 8 XCDs, 256-block chunks.
    const int bid = ((int)blockIdx.x & 7) * ((int)gridDim.x >> 3)
                  + ((int)blockIdx.x >> 3);
    const int s0  = bid * NSITE_BLK;

    // ---- one-time staging ----
    {
        const int site = tid >> 3;       // 0..63
        const int r8   = tid & 7;        // 0..7

        // omega -> [mu][ik][j][i] (1280 floats)
        for (int t = tid; t < 1280; t += 512) {
            const int i  = t / 160;
            const int r  = t - i * 160;
            const int j  = r / 20;
            const int r2 = r - j * 20;
            const int m  = r2 / 5;
            const int ik = r2 - m * 5;
            lds[OM_OFF + m * 328 + ik * 64 + j * 8 + i] = omega[t];
        }

        // U slice: 64 sites x 45 float4 -> [site][184] (lane-linear, coalesced)
        const float4* __restrict__ U4 =
            reinterpret_cast<const float4*>(U_PT) + (size_t)s0 * 45;
#pragma unroll
        for (int st = 0; st < 6; ++st) {
            const int f4r = st * 8 + r8;
            if (st < 5 || f4r < 45) {
                *reinterpret_cast<float4*>(
                    lds + U_OFF + site * 184 + f4r * 4) =
                    U4[site * 45 + f4r];
            }
        }
    }
    __syncthreads();

    const int local = tid >> 3;          // 0..63 site local id
    const int s     = s0 + local;
    const int jh    = (tid >> 2) & 1;    // j-half AND i-half
    const int mu    = tid & 3;           // axis
    const int sh    = 12 - 4 * mu;       // bit position of x_mu in s
    const int x     = (s >> sh) & 15;

    const float* __restrict__ Ul  = lds + U_OFF + local * 184 + mu * 45;
    const float* __restrict__ omt = lds + OM_OFF + mu * 328 + jh * 4;
    const int jown8 = jh * 32;
    const int jpar8 = (jh ^ 1) * 32;

    float acc[4][9];
#pragma unroll
    for (int i = 0; i < 4; ++i)
#pragma unroll
        for (int e = 0; e < 9; ++e) acc[i][e] = 0.0f;

#pragma unroll 1
    for (int ik = 0; ik < 5; ++ik) {
        const int k = ik - 2;

        // neighbor site along mu (uniform, branch-free)
        const int ns = s + ((((x + k + 16) & 15) - x) << sh);
        const float4* __restrict__ Wp =
            reinterpret_cast<const float4*>(W + (size_t)ns * 72 + jh * 36);

        // U for this ik from LDS
        float U[9];
#pragma unroll
        for (int e = 0; e < 9; ++e) U[e] = Ul[ik * 9 + e];

        // channels streamed as JIT float4s (max ~3 live W-f4s):
        // ch0 = f0-8, ch1 = f9-17, ch2 = f18-26, ch3 = f27-35
        {
            const float4 a0 = Wp[0], a1 = Wp[1], a2 = Wp[2];
            DO_CH(0, a0.x, a0.y, a0.z, a0.w, a1.x, a1.y, a1.z, a1.w, a2.x);
            const float4 a3 = Wp[3], a4 = Wp[4];
            DO_CH(1, a2.y, a2.z, a2.w, a3.x, a3.y, a3.z, a3.w, a4.x, a4.y);
            const float4 a5 = Wp[5], a6 = Wp[6];
            DO_CH(2, a4.z, a4.w, a5.x, a5.y, a5.z, a5.w, a6.x, a6.y, a6.z);
            const float4 a7 = Wp[7], a8 = Wp[8];
            DO_CH(3, a6.w, a7.x, a7.y, a7.z, a7.w, a8.x, a8.y, a8.z, a8.w);
        }
    }

    // reduce the 4 mu-partials within each mu-quad
#pragma unroll
    for (int i = 0; i < 4; ++i)
#pragma unroll
        for (int e = 0; e < 9; ++e) {
            float v = acc[i][e];
            v += __shfl_xor(v, 1);
            v += __shfl_xor(v, 2);
            acc[i][e] = v;
        }

    // mu==0 lanes (2 per site) store their 36-float half-block (9 float4)
    if (mu == 0) {
        float4* __restrict__ o4 =
            reinterpret_cast<float4*>(out + (size_t)s * 72 + jh * 36);
#pragma unroll
        for (int q = 0; q < 9; ++q) {
            const int f = q * 4;
            o4[q] = make_float4(acc[(f + 0) / 9][(f + 0) % 9],
                                acc[(f + 1) / 9][(f + 1) % 9],
                                acc[(f + 2) / 9][(f + 2) % 9],
                                acc[(f + 3) / 9][(f + 3) % 9]);
        }
    }
}

extern "C" void kernel_launch(void* const* d_in, const int* in_sizes, int n_in,
                              void* d_out, int out_size, void* d_ws, size_t ws_size,
                              hipStream_t stream) {
    const float* W   = (const float*)d_in[0];
    const float* U   = (const float*)d_in[1];
    const float* om  = (const float*)d_in[2];
    float*       out = (float*)d_out;

    const int block = 512;
    const int grid  = NSITES / NSITE_BLK;   // 2048 blocks, 64 sites each
    hipLaunchKernelGGL(lconv_kernel, dim3(grid), dim3(block), 0, stream,
                       W, U, om, out);
}

// Round 16
// 223.297 us; speedup vs baseline: 2.1140x; 2.1140x over previous
//
#include <hip/hip_runtime.h>

// Problem constants (B=2, L=16, D=4, K=2, N_IN=8, N_OUT=8, NC=3)
#define NSITES (1 << 17)         // 131072 sites (2*16^4)
// W:     site-stride 72 floats (18 float4), base 288 B
// U_PT:  site-stride 180 floats
// omega: flat [i][j][mu][ik] (1280 floats)
// out:   site-stride 72 floats
//
// R16 = R14 body WITHOUT the launch_bounds force (R3/R14/R15 all proved
//   that forcing the 2nd arg makes the allocator overshoot into scratch).
//   16 threads/site = (q = output-i-pair, mu), MIX-FIRST:
//     V_i = sum_j omega[i,j] W_j   (thread-local, no in-loop shuffles)
//     acc_i += U V_i U^T
//   Natural live set ~50-60 VGPR -> hoping the allocator lands <=64
//   (the occupancy step: 4 -> 8 waves/SIMD). LDS = 17.0 KB.
//   The dur*VALUBusy ~= 48us law then predicts ~55-70us.

#define OM_OFF 0                 // [mu][ik][j][i]: mu-stride 328 (pad 320)
#define U_OFF  1312              // [site][184] (pad 180)
#define LDS_FLOATS (U_OFF + 16 * 184)   // 4256 floats = 17024 B

// V-mix for channel J: V{0,1}[e] (op)= omega[2q+{0,1}, J] * w[e]
#define MIX_CH(FIRST, J, w0,w1,w2,w3,w4,w5,w6,w7,w8) do {                    \
    const float2 o2 = *reinterpret_cast<const float2*>(                      \
                          omt + ik * 64 + (J) * 8);                          \
    const float wv[9] = {w0,w1,w2,w3,w4,w5,w6,w7,w8};                        \
    _Pragma("unroll")                                                        \
    for (int e = 0; e < 9; ++e) {                                            \
        if (FIRST) { V0[e] = o2.x * wv[e];                                   \
                     V1[e] = o2.y * wv[e]; }                                 \
        else       { V0[e] = fmaf(o2.x, wv[e], V0[e]);                       \
                     V1[e] = fmaf(o2.y, wv[e], V1[e]); }                     \
    }                                                                        \
} while (0)

// acc += U * V * U^T (final add folded into the fma chain)
#define SAND(Vv, av) do {                                                    \
    _Pragma("unroll")                                                        \
    for (int a = 0; a < 3; ++a) {                                            \
        const float uw0 = fmaf(U[a*3+0], Vv[0],                              \
                          fmaf(U[a*3+1], Vv[3], U[a*3+2] * Vv[6]));          \
        const float uw1 = fmaf(U[a*3+0], Vv[1],                              \
                          fmaf(U[a*3+1], Vv[4], U[a*3+2] * Vv[7]));          \
        const float uw2 = fmaf(U[a*3+0], Vv[2],                              \
                          fmaf(U[a*3+1], Vv[5], U[a*3+2] * Vv[8]));          \
        _Pragma("unroll")                                                    \
        for (int b = 0; b < 3; ++b)                                          \
            av[a*3+b] = fmaf(uw0, U[b*3+0],                                  \
                        fmaf(uw1, U[b*3+1],                                  \
                        fmaf(uw2, U[b*3+2], av[a*3+b])));                    \
    }                                                                        \
} while (0)

__global__ __launch_bounds__(256) void lconv_kernel(
    const float* __restrict__ W, const float* __restrict__ U_PT,
    const float* __restrict__ omega, float* __restrict__ out)
{
    __shared__ float lds[LDS_FLOATS];
    const int tid = threadIdx.x;

    // XCD-aware bijective swizzle: 8192 blocks, 8 XCDs, 1024-block chunks.
    const int bid = ((int)blockIdx.x & 7) * ((int)gridDim.x >> 3)
                  + ((int)blockIdx.x >> 3);
    const int s0  = bid * 16;            // 16 sites per block

    // ---- one-time staging ----
    {
        // omega -> [mu][ik][j][i]
        for (int t = tid; t < 1280; t += 256) {
            const int i  = t / 160;
            const int r  = t - i * 160;
            const int j  = r / 20;
            const int r2 = r - j * 20;
            const int m  = r2 / 5;
            const int ikk = r2 - m * 5;
            lds[OM_OFF + m * 328 + ikk * 64 + j * 8 + i] = omega[t];
        }
        // U slice: 16 sites x 45 float4 -> [site][184] (lane-linear)
        const int site = tid >> 4;       // 0..15
        const int r16  = tid & 15;       // 0..15
        const float4* __restrict__ U4 =
            reinterpret_cast<const float4*>(U_PT) + (size_t)s0 * 45;
#pragma unroll
        for (int st = 0; st < 3; ++st) {
            const int f4r = st * 16 + r16;
            if (st < 2 || f4r < 45) {
                *reinterpret_cast<float4*>(
                    lds + U_OFF + site * 184 + f4r * 4) =
                    U4[site * 45 + f4r];
            }
        }
    }
    __syncthreads();

    const int local = tid >> 4;          // site local id 0..15
    const int s     = s0 + local;
    const int q     = (tid >> 2) & 3;    // output-i pair: i = 2q, 2q+1
    const int mu    = tid & 3;           // axis
    const int sh    = 12 - 4 * mu;       // bit position of x_mu in s
    const int x     = (s >> sh) & 15;

    const float* __restrict__ Ul  = lds + U_OFF + local * 184 + mu * 45;
    const float* __restrict__ omt = lds + OM_OFF + mu * 328 + q * 2;

    float acc0[9], acc1[9];
#pragma unroll
    for (int e = 0; e < 9; ++e) { acc0[e] = 0.0f; acc1[e] = 0.0f; }

#pragma unroll 1
    for (int ik = 0; ik < 5; ++ik) {
        const int k = ik - 2;

        // neighbor site along mu (uniform, branch-free)
        const int ns = s + ((((x + k + 16) & 15) - x) << sh);
        const float4* __restrict__ Wp =
            reinterpret_cast<const float4*>(W + (size_t)ns * 72);

        // ---- mix: V_i = sum_j omega[i,j,mu,ik] * W_j  (18 f4 JIT stream;
        //      q lane-classes read identical addresses -> HW merges)
        float V0[9], V1[9];
        {
            const float4 a0 = Wp[0], a1 = Wp[1], a2 = Wp[2];
            MIX_CH(1, 0, a0.x,a0.y,a0.z,a0.w, a1.x,a1.y,a1.z,a1.w, a2.x);
            const float4 a3 = Wp[3], a4 = Wp[4];
            MIX_CH(0, 1, a2.y,a2.z,a2.w, a3.x,a3.y,a3.z,a3.w, a4.x,a4.y);
            const float4 a5 = Wp[5], a6 = Wp[6];
            MIX_CH(0, 2, a4.z,a4.w, a5.x,a5.y,a5.z,a5.w, a6.x,a6.y,a6.z);
            const float4 a7 = Wp[7], a8 = Wp[8];
            MIX_CH(0, 3, a6.w, a7.x,a7.y,a7.z,a7.w, a8.x,a8.y,a8.z,a8.w);
            const float4 a9 = Wp[9], a10 = Wp[10], a11 = Wp[11];
            MIX_CH(0, 4, a9.x,a9.y,a9.z,a9.w, a10.x,a10.y,a10.z,a10.w, a11.x);
            const float4 a12 = Wp[12], a13 = Wp[13];
            MIX_CH(0, 5, a11.y,a11.z,a11.w, a12.x,a12.y,a12.z,a12.w, a13.x,a13.y);
            const float4 a14 = Wp[14], a15 = Wp[15];
            MIX_CH(0, 6, a13.z,a13.w, a14.x,a14.y,a14.z,a14.w, a15.x,a15.y,a15.z);
            const float4 a16 = Wp[16], a17 = Wp[17];
            MIX_CH(0, 7, a15.w, a16.x,a16.y,a16.z,a16.w, a17.x,a17.y,a17.z,a17.w);
        }

        // ---- U for this (site, mu, ik) from LDS
        float U[9];
#pragma unroll
        for (int e = 0; e < 9; ++e) U[e] = Ul[ik * 9 + e];

        // ---- sandwich-accumulate both owned output channels
        SAND(V0, acc0);
        SAND(V1, acc1);
    }

    // reduce the 4 mu-partials within each mu-quad (lane bits 0,1)
#pragma unroll
    for (int e = 0; e < 9; ++e) {
        float v0 = acc0[e];
        v0 += __shfl_xor(v0, 1);
        v0 += __shfl_xor(v0, 2);
        acc0[e] = v0;
        float v1 = acc1[e];
        v1 += __shfl_xor(v1, 1);
        v1 += __shfl_xor(v1, 2);
        acc1[e] = v1;
    }

    // mu==0 lanes (4 per site) store their i-pair: 18 floats = 9 float2
    if (mu == 0) {
        float2* __restrict__ o2 =
            reinterpret_cast<float2*>(out + (size_t)s * 72 + q * 18);
        o2[0] = make_float2(acc0[0], acc0[1]);
        o2[1] = make_float2(acc0[2], acc0[3]);
        o2[2] = make_float2(acc0[4], acc0[5]);
        o2[3] = make_float2(acc0[6], acc0[7]);
        o2[4] = make_float2(acc0[8], acc1[0]);
        o2[5] = make_float2(acc1[1], acc1[2]);
        o2[6] = make_float2(acc1[3], acc1[4]);
        o2[7] = make_float2(acc1[5], acc1[6]);
        o2[8] = make_float2(acc1[7], acc1[8]);
    }
}

extern "C" void kernel_launch(void* const* d_in, const int* in_sizes, int n_in,
                              void* d_out, int out_size, void* d_ws, size_t ws_size,
                              hipStream_t stream) {
    const float* W   = (const float*)d_in[0];
    const float* U   = (const float*)d_in[1];
    const float* om  = (const float*)d_in[2];
    float*       out = (float*)d_out;

    const int block = 256;
    const int grid  = NSITES / 16;    // 8192 blocks, 16 sites each
    hipLaunchKernelGGL(lconv_kernel, dim3(grid), dim3(block), 0, stream,
                       W, U, om, out);
}

// Round 17
// 120.465 us; speedup vs baseline: 3.9186x; 1.8536x over previous
//
#include <hip/hip_runtime.h>

// Problem constants (B=2, L=16, D=4, K=2, N_IN=8, N_OUT=8, NC=3)
#define NSITES (1 << 17)         // 131072 sites (2*16^4)
// W:     site-stride 72 floats (18 float4), base 288 B
// U_PT:  site-stride 180 floats
// omega: flat [i][j][mu][ik] (1280 floats)
// out:   site-stride 72 floats
//
// R17 = R11 (cross-ik A5/B4 register pipeline, correctness-proven) +
//   __builtin_amdgcn_sched_barrier(0) pinning the issue order so the
//   compiler cannot sink the prefetch loads to their use sites (which
//   erased R7/R11's pipelines -- VGPR stayed 72, proving the sink).
//   Issue {B f4 5..8, N = next-ik f4 0..4, U ds_reads} -> SCHED_BARRIER ->
//   consume A (loaded LAST iter, vmcnt(9)) / B (vmcnt(5), ~430cyc cover).
//   This is the counted-vmcnt idiom in plain HIP.

#define OM_OFF 0                 // 4*328 = 1312 floats
#define U_OFF  1312              // 32*184 = 5888 floats
#define LDS_FLOATS (U_OFF + 5888)   // 7200 floats = 28800 B

#define SCHED_PIN() __builtin_amdgcn_sched_barrier(0)

// sandwich channel T (9 row-major floats) + omega-mix into acc
#define DO_CH(T, w0,w1,w2,w3,w4,w5,w6,w7,w8) do {                           \
    float M[9];                                                             \
    _Pragma("unroll")                                                       \
    for (int a = 0; a < 3; ++a) {                                           \
        const float uw0 = fmaf(U[a*3+0], (w0),                              \
                          fmaf(U[a*3+1], (w3), U[a*3+2] * (w6)));           \
        const float uw1 = fmaf(U[a*3+0], (w1),                              \
                          fmaf(U[a*3+1], (w4), U[a*3+2] * (w7)));           \
        const float uw2 = fmaf(U[a*3+0], (w2),                              \
                          fmaf(U[a*3+1], (w5), U[a*3+2] * (w8)));           \
        _Pragma("unroll")                                                   \
        for (int b2 = 0; b2 < 3; ++b2)                                      \
            M[a*3+b2] = fmaf(uw0, U[b2*3+0],                                \
                        fmaf(uw1, U[b2*3+1], uw2 * U[b2*3+2]));             \
    }                                                                       \
    const float4 wo = *reinterpret_cast<const float4*>(                     \
                          omt + ik * 64 + jown8 + (T) * 8);                 \
    const float4 wp = *reinterpret_cast<const float4*>(                     \
                          omt + ik * 64 + jpar8 + (T) * 8);                 \
    const float wov[4] = {wo.x, wo.y, wo.z, wo.w};                          \
    const float wpv[4] = {wp.x, wp.y, wp.z, wp.w};                          \
    _Pragma("unroll")                                                       \
    for (int e = 0; e < 9; ++e) {                                           \
        const float mp = __shfl_xor(M[e], 4);                               \
        _Pragma("unroll")                                                   \
        for (int ii = 0; ii < 4; ++ii)                                      \
            acc[ii][e] = fmaf(wov[ii], M[e], fmaf(wpv[ii], mp, acc[ii][e]));\
    }                                                                       \
} while (0)

__global__ __launch_bounds__(256) void lconv_kernel(
    const float* __restrict__ W, const float* __restrict__ U_PT,
    const float* __restrict__ omega, float* __restrict__ out)
{
    __shared__ float lds[LDS_FLOATS];
    const int tid = threadIdx.x;

    // XCD-aware bijective swizzle: 4096 blocks, 8 XCDs, 512-block chunks.
    const int bid = ((int)blockIdx.x & 7) * ((int)gridDim.x >> 3)
                  + ((int)blockIdx.x >> 3);
    const int s0  = bid * 32;

    // ---- one-time staging ----
    {
        const int site = tid >> 3;       // 0..31
        const int r8   = tid & 7;        // 0..7

        // omega -> [mu][ik][j][i] (1280 floats)
        for (int t = tid; t < 1280; t += 256) {
            const int i  = t / 160;
            const int r  = t - i * 160;
            const int j  = r / 20;
            const int r2 = r - j * 20;
            const int m  = r2 / 5;
            const int ik = r2 - m * 5;
            lds[OM_OFF + m * 328 + ik * 64 + j * 8 + i] = omega[t];
        }

        // U slice: 32 sites x 45 float4 -> [site][184] (lane-linear)
        const float4* __restrict__ U4 =
            reinterpret_cast<const float4*>(U_PT) + (size_t)s0 * 45;
#pragma unroll
        for (int st = 0; st < 6; ++st) {
            const int f4r = st * 8 + r8;
            if (st < 5 || f4r < 45) {
                *reinterpret_cast<float4*>(
                    lds + U_OFF + site * 184 + f4r * 4) =
                    U4[site * 45 + f4r];
            }
        }
    }
    __syncthreads();

    const int local = tid >> 3;          // 0..31 site local id
    const int s     = s0 + local;
    const int jh    = (tid >> 2) & 1;    // j-half AND i-half
    const int mu    = tid & 3;           // axis
    const int sh    = 12 - 4 * mu;       // bit position of x_mu in s
    const int x     = (s >> sh) & 15;

    const float* __restrict__ Ul  = lds + U_OFF + local * 184 + mu * 45;
    const float* __restrict__ omt = lds + OM_OFF + mu * 328 + jh * 4;
    const int jown8 = jh * 32;
    const int jpar8 = (jh ^ 1) * 32;

    float acc[4][9];
#pragma unroll
    for (int i = 0; i < 4; ++i)
#pragma unroll
        for (int e = 0; e < 9; ++e) acc[i][e] = 0.0f;

    // neighbor half-block base for shift k
    const float* base0 = W + (size_t)s * 72 + jh * 36;
#define NBASE(kk) reinterpret_cast<const float4*>( \
        base0 + ((((((x + (kk) + 16) & 15) - x)) << sh) * 72))

    // ---- prologue: A = f4 0..4 of ik=0 (k=-2), pinned ----
    const float4* pcur = NBASE(-2);
    float4 A0 = pcur[0], A1 = pcur[1], A2 = pcur[2], A3 = pcur[3], A4 = pcur[4];
    SCHED_PIN();

#pragma unroll 1
    for (int ik = 0; ik < 5; ++ik) {
        const int kn = ((ik < 4) ? ik + 1 : ik) - 2;   // next-ik shift (clamped)
        const float4* pnext = NBASE(kn);

        // B: rest of current half (f4 5..8), first used at DO_CH(2)
        const float4 B0 = pcur[5], B1 = pcur[6], B2 = pcur[7], B3 = pcur[8];
        // N: next ik's f4 0..4, used next iteration
        const float4 N0 = pnext[0], N1 = pnext[1], N2 = pnext[2],
                     N3 = pnext[3], N4 = pnext[4];
        // U for this ik from LDS
        float U[9];
#pragma unroll
        for (int e = 0; e < 9; ++e) U[e] = Ul[ik * 9 + e];

        // pin: all loads above are ISSUED before any compute below;
        // waitcnts still land at first use (A: vmcnt(9), B: vmcnt(5)).
        SCHED_PIN();

        // channel floats (row-major 3x3 each):
        // ch0 = f0-8, ch1 = f9-17, ch2 = f18-26, ch3 = f27-35
        DO_CH(0, A0.x, A0.y, A0.z, A0.w, A1.x, A1.y, A1.z, A1.w, A2.x);
        DO_CH(1, A2.y, A2.z, A2.w, A3.x, A3.y, A3.z, A3.w, A4.x, A4.y);
        DO_CH(2, A4.z, A4.w, B0.x, B0.y, B0.z, B0.w, B1.x, B1.y, B1.z);
        DO_CH(3, B1.w, B2.x, B2.y, B2.z, B2.w, B3.x, B3.y, B3.z, B3.w);

        // rotate pipeline
        A0 = N0; A1 = N1; A2 = N2; A3 = N3; A4 = N4;
        pcur = pnext;
    }

    // reduce the 4 mu-partials within each mu-quad
#pragma unroll
    for (int i = 0; i < 4; ++i)
#pragma unroll
        for (int e = 0; e < 9; ++e) {
            float v = acc[i][e];
            v += __shfl_xor(v, 1);
            v += __shfl_xor(v, 2);
            acc[i][e] = v;
        }

    // mu==0 lanes (2 per site) store their 36-float half-block (9 float4)
    if (mu == 0) {
        float4* __restrict__ o4 =
            reinterpret_cast<float4*>(out + (size_t)s * 72 + jh * 36);
#pragma unroll
        for (int q = 0; q < 9; ++q) {
            const int f = q * 4;
            o4[q] = make_float4(acc[(f + 0) / 9][(f + 0) % 9],
                                acc[(f + 1) / 9][(f + 1) % 9],
                                acc[(f + 2) / 9][(f + 2) % 9],
                                acc[(f + 3) / 9][(f + 3) % 9]);
        }
    }
}

extern "C" void kernel_launch(void* const* d_in, const int* in_sizes, int n_in,
                              void* d_out, int out_size, void* d_ws, size_t ws_size,
                              hipStream_t stream) {
    const float* W   = (const float*)d_in[0];
    const float* U   = (const float*)d_in[1];
    const float* om  = (const float*)d_in[2];
    float*       out = (float*)d_out;

    const int block = 256;
    const int grid  = NSITES / 32;    // 4096 blocks, 32 sites each
    hipLaunchKernelGGL(lconv_kernel, dim3(grid), dim3(block), 0, stream,
                       W, U, om, out);
}

// Round 18
// 110.014 us; speedup vs baseline: 4.2909x; 1.0950x over previous
//
#include <hip/hip_runtime.h>

// Problem constants (B=2, L=16, D=4, K=2, N_IN=8, N_OUT=8, NC=3)
#define NSITES (1 << 17)         // 131072 sites (2*16^4)
// W:     site-stride 72 floats (18 float4), base 288 B
// U_PT:  site-stride 180 floats
// omega: flat [i][j][mu][ik] (1280 floats)
// out:   site-stride 72 floats
//
// R18 = R12 with the M[9] array ELIMINATED (elementwise sandwich fused
//   with the mix): per (a,b) the scalar m is computed, shfl-exchanged,
//   consumed into 8 acc-FMAs, and dies. Target: natural VGPR <= 64.
//   m69 occupancy law: waves/CU cap = 32 at VGPR<=64, 16 at 65-128.
//   R10/R12 sit at 72 -> 16-wave cap -> VALUBusy ~46%. This body keeps
//   R12's minimal vmem count (9 insts/ik/wave, zero duplication) and
//   sheds the last persistent registers. NO launch_bounds forcing
//   (R3/R14/R15: forcing = allocator overshoot into scratch).

#define OM_OFF 0                 // [mu][ik][j][i]: mu-stride 328
#define U_OFF  1312              // [site][184] (pad 180)
#define LDS_FLOATS (U_OFF + 5888)   // 7200 floats = 28800 B

// elementwise sandwich + fused omega-mix for one channel (9 floats w0..w8)
#define DO_CH_E(T, w0,w1,w2,w3,w4,w5,w6,w7,w8) do {                         \
    const float4 wo = *reinterpret_cast<const float4*>(                     \
                          omt + ik * 64 + jown8 + (T) * 8);                 \
    const float4 wp = *reinterpret_cast<const float4*>(                     \
                          omt + ik * 64 + jpar8 + (T) * 8);                 \
    const float wov[4] = {wo.x, wo.y, wo.z, wo.w};                          \
    const float wpv[4] = {wp.x, wp.y, wp.z, wp.w};                          \
    _Pragma("unroll")                                                       \
    for (int a = 0; a < 3; ++a) {                                           \
        const float uw0 = fmaf(U[a*3+0], (w0),                              \
                          fmaf(U[a*3+1], (w3), U[a*3+2] * (w6)));           \
        const float uw1 = fmaf(U[a*3+0], (w1),                              \
                          fmaf(U[a*3+1], (w4), U[a*3+2] * (w7)));           \
        const float uw2 = fmaf(U[a*3+0], (w2),                              \
                          fmaf(U[a*3+1], (w5), U[a*3+2] * (w8)));           \
        _Pragma("unroll")                                                   \
        for (int b2 = 0; b2 < 3; ++b2) {                                    \
            const float m  = fmaf(uw0, U[b2*3+0],                           \
                             fmaf(uw1, U[b2*3+1], uw2 * U[b2*3+2]));        \
            const float mp = __shfl_xor(m, 4);                              \
            _Pragma("unroll")                                               \
            for (int ii = 0; ii < 4; ++ii)                                  \
                acc[ii][a*3+b2] = fmaf(wov[ii], m,                          \
                                  fmaf(wpv[ii], mp, acc[ii][a*3+b2]));      \
        }                                                                   \
    }                                                                       \
} while (0)

__global__ __launch_bounds__(256) void lconv_kernel(
    const float* __restrict__ W, const float* __restrict__ U_PT,
    const float* __restrict__ omega, float* __restrict__ out)
{
    __shared__ float lds[LDS_FLOATS];
    const int tid = threadIdx.x;

    // XCD-aware bijective swizzle: 4096 blocks, 8 XCDs, 512-block chunks.
    const int bid = ((int)blockIdx.x & 7) * ((int)gridDim.x >> 3)
                  + ((int)blockIdx.x >> 3);
    const int s0  = bid * 32;

    // ---- one-time staging ----
    {
        const int site = tid >> 3;       // 0..31
        const int r8   = tid & 7;        // 0..7

        // omega -> [mu][ik][j][i] (1280 floats)
        for (int t = tid; t < 1280; t += 256) {
            const int i  = t / 160;
            const int r  = t - i * 160;
            const int j  = r / 20;
            const int r2 = r - j * 20;
            const int m  = r2 / 5;
            const int ik = r2 - m * 5;
            lds[OM_OFF + m * 328 + ik * 64 + j * 8 + i] = omega[t];
        }

        // U slice: 32 sites x 45 float4 -> [site][184] (lane-linear)
        const float4* __restrict__ U4 =
            reinterpret_cast<const float4*>(U_PT) + (size_t)s0 * 45;
#pragma unroll
        for (int st = 0; st < 6; ++st) {
            const int f4r = st * 8 + r8;
            if (st < 5 || f4r < 45) {
                *reinterpret_cast<float4*>(
                    lds + U_OFF + site * 184 + f4r * 4) =
                    U4[site * 45 + f4r];
            }
        }
    }
    __syncthreads();

    const int local = tid >> 3;          // 0..31 site local id
    const int s     = s0 + local;
    const int jh    = (tid >> 2) & 1;    // j-half AND i-half
    const int mu    = tid & 3;           // axis
    const int sh    = 12 - 4 * mu;       // bit position of x_mu in s
    const int x     = (s >> sh) & 15;

    const float* __restrict__ Ul  = lds + U_OFF + local * 184 + mu * 45;
    const float* __restrict__ omt = lds + OM_OFF + mu * 328 + jh * 4;
    const int jown8 = jh * 32;
    const int jpar8 = (jh ^ 1) * 32;

    float acc[4][9];
#pragma unroll
    for (int i = 0; i < 4; ++i)
#pragma unroll
        for (int e = 0; e < 9; ++e) acc[i][e] = 0.0f;

#pragma unroll 1
    for (int ik = 0; ik < 5; ++ik) {
        const int k = ik - 2;

        // neighbor site along mu (uniform, branch-free)
        const int ns = s + ((((x + k + 16) & 15) - x) << sh);
        const float4* __restrict__ Wp =
            reinterpret_cast<const float4*>(W + (size_t)ns * 72 + jh * 36);

        // U for this ik from LDS
        float U[9];
#pragma unroll
        for (int e = 0; e < 9; ++e) U[e] = Ul[ik * 9 + e];

        // channels streamed as JIT float4s (max ~3 live W-f4s):
        // ch0 = f0-8, ch1 = f9-17, ch2 = f18-26, ch3 = f27-35
        {
            const float4 a0 = Wp[0], a1 = Wp[1], a2 = Wp[2];
            DO_CH_E(0, a0.x, a0.y, a0.z, a0.w, a1.x, a1.y, a1.z, a1.w, a2.x);
            const float4 a3 = Wp[3], a4 = Wp[4];
            DO_CH_E(1, a2.y, a2.z, a2.w, a3.x, a3.y, a3.z, a3.w, a4.x, a4.y);
            const float4 a5 = Wp[5], a6 = Wp[6];
            DO_CH_E(2, a4.z, a4.w, a5.x, a5.y, a5.z, a5.w, a6.x, a6.y, a6.z);
            const float4 a7 = Wp[7], a8 = Wp[8];
            DO_CH_E(3, a6.w, a7.x, a7.y, a7.z, a7.w, a8.x, a8.y, a8.z, a8.w);
        }
    }

    // reduce the 4 mu-partials within each mu-quad
#pragma unroll
    for (int i = 0; i < 4; ++i)
#pragma unroll
        for (int e = 0; e < 9; ++e) {
            float v = acc[i][e];
            v += __shfl_xor(v, 1);
            v += __shfl_xor(v, 2);
            acc[i][e] = v;
        }

    // mu==0 lanes (2 per site) store their 36-float half-block (9 float4)
    if (mu == 0) {
        float4* __restrict__ o4 =
            reinterpret_cast<float4*>(out + (size_t)s * 72 + jh * 36);
#pragma unroll
        for (int q = 0; q < 9; ++q) {
            const int f = q * 4;
            o4[q] = make_float4(acc[(f + 0) / 9][(f + 0) % 9],
                                acc[(f + 1) / 9][(f + 1) % 9],
                                acc[(f + 2) / 9][(f + 2) % 9],
                                acc[(f + 3) / 9][(f + 3) % 9]);
        }
    }
}

extern "C" void kernel_launch(void* const* d_in, const int* in_sizes, int n_in,
                              void* d_out, int out_size, void* d_ws, size_t ws_size,
                              hipStream_t stream) {
    const float* W   = (const float*)d_in[0];
    const float* U   = (const float*)d_in[1];
    const float* om  = (const float*)d_in[2];
    float*       out = (float*)d_out;

    const int block = 256;
    const int grid  = NSITES / 32;    // 4096 blocks, 32 sites each
    hipLaunchKernelGGL(lconv_kernel, dim3(grid), dim3(block), 0, stream,
                       W, U, om, out);
}